// Round 1
// baseline (14.127 us; speedup 1.0000x reference)
//
#include <hip/hip_runtime.h>
#include <math.h>

#define NUM_CLASSES 4
#define EPS 1e-7f
#define B_ 64
#define T_ 50
#define NNEG 500
#define NA 38   // positive blocks: 38*256 = 9728 >= 9600
#define NB 128  // negative blocks (grid-stride over 96000)

__device__ __forceinline__ float softplusf(float x) {
    // matches jax.nn.softplus = logaddexp(x, 0)
    return fmaxf(x, 0.0f) + log1pf(expf(-fabsf(x)));
}

__device__ __forceinline__ float block_reduce256(float v, float* sdata) {
    int t = threadIdx.x;
    sdata[t] = v;
    __syncthreads();
    for (int s = 128; s > 0; s >>= 1) {
        if (t < s) sdata[t] += sdata[t + s];
        __syncthreads();
    }
    float r = sdata[0];
    __syncthreads();
    return r;
}

__global__ void __launch_bounds__(256) yolo_main(
        const float* __restrict__ pr3, const float* __restrict__ pr4,
        const float* __restrict__ pr5, const float* __restrict__ targets,
        const float* __restrict__ anchors,
        const int* __restrict__ ng3, const int* __restrict__ ng4,
        const int* __restrict__ ng5, float* __restrict__ ws) {
    __shared__ float sred[256];

    if (blockIdx.x < NA) {
        // ---------------- positive targets: 3 scales * 64 * 50 = 9600 ----
        float box = 0.f, cls = 0.f, conf = 0.f, nv = 0.f;
        int idx = blockIdx.x * 256 + threadIdx.x;
        if (idx < 3 * B_ * T_) {
            int s   = idx / (B_ * T_);
            int rem = idx - s * (B_ * T_);
            int b   = rem / T_;
            int t   = rem - b * T_;

            int hw = (s == 0) ? 80 : ((s == 1) ? 40 : 20);
            const float* pred = (s == 0) ? pr3 : ((s == 1) ? pr4 : pr5);
            int a0 = 3 * s;

            const float* tg = targets + (size_t)(b * T_ + t) * 5;
            float clsf = tg[0], tx = tg[1], ty = tg[2], tw = tg[3], th = tg[4];

            bool valid = (tx >= 0.f) && (tx <= 1.f) && (ty >= 0.f) && (ty <= 1.f) &&
                         (tw > 0.f)  && (tw <= 1.f) && (th > 0.f)  && (th <= 1.f);

            // best-anchor argmax (first max wins, like jnp.argmax)
            int best = 0; float bestv = -1.f, awb = 0.f, ahb = 0.f;
            #pragma unroll
            for (int a = 0; a < 3; ++a) {
                float aw = anchors[(a0 + a) * 2 + 0] / 640.0f;
                float ah = anchors[(a0 + a) * 2 + 1] / 640.0f;
                float inter = fminf(tw, aw) * fminf(th, ah);
                float uni   = tw * th + aw * ah - inter;
                float r     = inter / (uni + EPS);
                if (r > bestv) { bestv = r; best = a; awb = aw; ahb = ah; }
            }

            int w = hw, h = hw;
            int gxi = (int)floorf(tx * (float)w); gxi = min(max(gxi, 0), w - 1);
            int gyi = (int)floorf(ty * (float)h); gyi = min(max(gyi, 0), h - 1);

            size_t chs = (size_t)h * (size_t)w;
            const float* base = pred + ((size_t)(b * 27 + best * 9) * (size_t)h + (size_t)gyi) * (size_t)w + (size_t)gxi;
            float c0 = base[0 * chs], c1 = base[1 * chs], c2 = base[2 * chs];
            float c3 = base[3 * chs], zc = base[4 * chs];
            float z0 = base[5 * chs], z1 = base[6 * chs];
            float z2 = base[7 * chs], z3 = base[8 * chs];

            float px  = 1.f / (1.f + expf(-c0)) + (float)gxi / (float)w;
            float py  = 1.f / (1.f + expf(-c1)) + (float)gyi / (float)h;
            float pw_ = expf(c2) * awb;
            float ph_ = expf(c3) * ahb;

            // GIoU
            float x1n = px - pw_ * 0.5f, x1x = px + pw_ * 0.5f;
            float y1n = py - ph_ * 0.5f, y1x = py + ph_ * 0.5f;
            float x2n = tx - tw * 0.5f,  x2x = tx + tw * 0.5f;
            float y2n = ty - th * 0.5f,  y2x = ty + th * 0.5f;
            float iw = fmaxf(fminf(x1x, x2x) - fmaxf(x1n, x2n), 0.f);
            float ih = fmaxf(fminf(y1x, y2x) - fmaxf(y1n, y2n), 0.f);
            float inter = iw * ih;
            float uni = pw_ * ph_ + tw * th - inter + EPS;
            float iou = inter / uni;
            float ew = fmaxf(x1x, x2x) - fminf(x1n, x2n);
            float eh = fmaxf(y1x, y2x) - fminf(y1n, y2n);
            float enclose = ew * eh + EPS;
            float giou = iou - (enclose - uni) / enclose;

            int cid = (int)clsf;
            float mask = (valid && (cid < NUM_CLASSES)) ? 1.f : 0.f;

            box = mask * (1.f - giou);

            // mean over 4 classes of softplus(z) - onehot*z
            float sbce = softplusf(z0) + softplusf(z1) + softplusf(z2) + softplusf(z3);
            float zsel = (cid == 0) ? z0 : (cid == 1) ? z1 : (cid == 2) ? z2 : (cid == 3) ? z3 : 0.f;
            cls = mask * 0.25f * (sbce - zsel);

            float conf_t = fminf(fmaxf(giou, 0.f), 1.f);
            conf = mask * (softplusf(zc) - conf_t * zc);

            nv = valid ? 1.f : 0.f;
        }
        float rb = block_reduce256(box,  sred);
        float rc = block_reduce256(cls,  sred);
        float rf = block_reduce256(conf, sred);
        float rn = block_reduce256(nv,   sred);
        if (threadIdx.x == 0) {
            float* w4 = ws + (size_t)blockIdx.x * 4;
            w4[0] = rb; w4[1] = rc; w4[2] = rf; w4[3] = rn;
        }
    } else {
        // ---------------- negative conf: 3 scales * 64 * 500 = 96000 -----
        float acc = 0.f;
        const int total = 3 * B_ * NNEG;
        for (int i = (blockIdx.x - NA) * 256 + threadIdx.x; i < total; i += NB * 256) {
            int s   = i / (B_ * NNEG);
            int rem = i - s * (B_ * NNEG);
            int b   = rem / NNEG;
            int j   = rem - b * NNEG;

            int hw = (s == 0) ? 80 : ((s == 1) ? 40 : 20);
            int chs = hw * hw;
            const float* pred = (s == 0) ? pr3 : ((s == 1) ? pr4 : pr5);
            const int* nix = (s == 0) ? ng3 : ((s == 1) ? ng4 : ng5);

            int id = nix[b * NNEG + j];        // in [0, 3*h*w)
            int a   = id / chs;
            int pos = id - a * chs;
            float z = pred[(size_t)(b * 27 + a * 9 + 4) * (size_t)chs + (size_t)pos];
            acc += softplusf(z);
        }
        float r = block_reduce256(acc, sred);
        if (threadIdx.x == 0) ws[NA * 4 + (blockIdx.x - NA)] = r;
    }
}

__global__ void __launch_bounds__(256) yolo_final(const float* __restrict__ ws,
                                                  float* __restrict__ out) {
    __shared__ float sb[256], sc[256], sf[256], sn[256], sg[256];
    int t = threadIdx.x;
    float b = 0.f, c = 0.f, f = 0.f, n = 0.f;
    if (t < NA) {
        b = ws[t * 4 + 0]; c = ws[t * 4 + 1];
        f = ws[t * 4 + 2]; n = ws[t * 4 + 3];
    }
    float g = (t < NB) ? ws[NA * 4 + t] : 0.f;
    sb[t] = b; sc[t] = c; sf[t] = f; sn[t] = n; sg[t] = g;
    __syncthreads();
    for (int s = 128; s > 0; s >>= 1) {
        if (t < s) {
            sb[t] += sb[t + s]; sc[t] += sc[t + s]; sf[t] += sf[t + s];
            sn[t] += sn[t + s]; sg[t] += sg[t + s];
        }
        __syncthreads();
    }
    if (t == 0) {
        float box = sb[0], cls = sc[0], conf = sf[0], nn = sn[0], negsum = sg[0];
        float denom = fmaxf(nn, 1.f);
        if (nn > 0.f) { box /= denom; cls /= denom; conf /= denom; }
        // reference: per scale 0.5 * sum_b(mean_j softplus) / (B*NNEG); factor
        // identical for all 3 scales -> fold into one.
        float neg = 0.5f * negsum / ((float)NNEG * (float)(B_ * NNEG));
        conf += neg;
        float total = box + cls + conf;
        out[0] = total; out[1] = box; out[2] = cls; out[3] = conf;
    }
}

extern "C" void kernel_launch(void* const* d_in, const int* in_sizes, int n_in,
                              void* d_out, int out_size, void* d_ws, size_t ws_size,
                              hipStream_t stream) {
    const float* p3      = (const float*)d_in[0];
    const float* p4      = (const float*)d_in[1];
    const float* p5      = (const float*)d_in[2];
    const float* targets = (const float*)d_in[3];
    const float* anchors = (const float*)d_in[4];
    const int*   ng3     = (const int*)d_in[5];
    const int*   ng4     = (const int*)d_in[6];
    const int*   ng5     = (const int*)d_in[7];

    float* ws  = (float*)d_ws;
    float* out = (float*)d_out;

    yolo_main<<<dim3(NA + NB), dim3(256), 0, stream>>>(
        p3, p4, p5, targets, anchors, ng3, ng4, ng5, ws);
    yolo_final<<<dim3(1), dim3(256), 0, stream>>>(ws, out);
}